// Round 4
// baseline (350.948 us; speedup 1.0000x reference)
//
#include <hip/hip_runtime.h>
#include <stdint.h>

// Problem: KS=3, ST=2, PAD=1, H=W=28, C=768, NH=12, hh=ww=14, dh=64.
//
// R7: R5/R6 counters both show ~800 resident blocks (occ 28-31%) regardless
// of block lifetime -> residency = CP dispatch rate x lifetime, NOT resource
// limited (VGPR=68 allows ~2560). Fix: persistent-shaped grid. 1792 blocks
// (= 7 blocks/CU, all co-resident), each owns 7 consecutive quads of ONE row
// (196 = 28*7: block's quads share qy and image b -> row pointers + row
// validity hoisted; adjacent quads share L2 lines). No retire-refill during
// the kernel; waves get 7 quads of independent work so quad t+1's 25 tap
// loads overlap quad t's FMAs.
//
// Quad formulation (from R6, verified): block computes 2x2 output pixels
// (y0,x0)=(2qy,2qx) sharing one 5x5 float4 tap window; the contributing
// (kh,kw) combos are 9 fixed attn runs with compile-time p and tap offsets:
//   P(0,0): p=4@(qy,qx)
//   P(0,1): p=5@(qy,qx); p=3@(qy,qx+1) if qx<13
//   P(1,0): p=7@(qy,qx); p=1@(qy+1,qx) if qy<13
//   P(1,1): p=8@(qy,qx); p=6@(qy,qx+1) if qx<13;
//           p=2@(qy+1,qx) if qy<13; p=0@(qy+1,qx+1) if both
// vv zero-padding handled by zeroing OOB taps (row part block-uniform).
#define HOUT 28
#define HH   14
#define NHEADS 12
#define CC   768
#define NPIX (HOUT * HOUT)   // 784
#define NQ   (HH * HH)       // 196 quads per image
#define AHW  (NHEADS * 81)   // attn stride per (h,w)

// acc += sum_{qh,qw} ap[3*qh+qw] * v[IO+qh][JO+qw]   (IO/JO compile-time)
template<int IO, int JO>
__device__ __forceinline__ void fma9(float4& acc,
                                     const float* __restrict__ ap,
                                     const float4 (&v)[5][5])
{
    #pragma unroll
    for (int qh = 0; qh < 3; ++qh)
        #pragma unroll
        for (int qw = 0; qw < 3; ++qw) {
            const float  a = ap[3 * qh + qw];
            const float4 u = v[IO + qh][JO + qw];
            acc.x = fmaf(a, u.x, acc.x);
            acc.y = fmaf(a, u.y, acc.y);
            acc.z = fmaf(a, u.z, acc.z);
            acc.w = fmaf(a, u.w, acc.w);
        }
}

__global__ __launch_bounds__(192)
void UnfoldMatmulFold_kernel(const float* __restrict__ vv,
                             const float* __restrict__ attn,
                             float* __restrict__ out)
{
    // XCD-aware decode: (id & 7) == (b & 7); g = id>>3 in [0,224):
    // bgrp = g/28, m = g%28 -> qy = m>>1, qx0 = (m&1)*7. All 7 quads of this
    // block: (qy, qx0..qx0+6) of image b.
    const unsigned id   = blockIdx.x;          // 0..1791
    const unsigned xcd  = id & 7u;
    const unsigned g    = id >> 3;             // 0..223
    const unsigned bgrp = g / 28u;             // 0..7
    const unsigned m    = g - bgrp * 28u;      // 0..27
    const int b   = (int)((bgrp << 3) | xcd);
    const int qy  = (int)(m >> 1);             // 0..13
    const int qx0 = (int)((m & 1u) * 7u);      // 0 or 7
    const int y0  = qy << 1;

    const int tid = threadIdx.x;     // 0..191
    const int c4  = tid << 2;        // 4 channels per thread
    const int n   = tid >> 4;        // head (64 ch = 16 threads per head)

    const float* vb = vv + (size_t)b * (NPIX * CC) + c4;

    // Row pointers + validity: fixed for the whole block (qy fixed).
    const float* vrow[5];
    bool rowok[5];
    #pragma unroll
    for (int i = 0; i < 5; ++i) {
        const int r  = y0 - 1 + i;
        rowok[i]     = ((unsigned)r < HOUT);
        const int rs = rowok[i] ? r : y0;
        vrow[i] = vb + (size_t)(rs * HOUT) * CC;
    }
    const bool hasY = (qy < 13);

    // attn base for (qy, qx0); advances by AHW per quad step.
    const float* abq = attn + (size_t)b * (NQ * AHW) + n * 81
                     + (size_t)(qy * HH + qx0) * AHW;

    const size_t obrow = (((size_t)b * HOUT + y0) * HOUT) * CC + c4;

    #pragma unroll 1      // keep VGPR low; TLP + cross-iter overlap do the rest
    for (int t = 0; t < 7; ++t) {
        const int qx = qx0 + t;
        const int x0 = qx << 1;

        // ---- 5x5 tap window: 25 independent float4 loads. ----
        float4 v[5][5];
        #pragma unroll
        for (int i = 0; i < 5; ++i) {
            #pragma unroll
            for (int jj = 0; jj < 5; ++jj) {
                const int cpos = x0 - 1 + jj;
                const int cs   = ((unsigned)cpos < HOUT) ? cpos : x0;
                v[i][jj] = *(const float4*)(vrow[i] + (size_t)cs * CC);
            }
        }
        // Zero OOB taps (vv zero-padding). Row part block-uniform.
        #pragma unroll
        for (int i = 0; i < 5; ++i) {
            #pragma unroll
            for (int jj = 0; jj < 5; ++jj) {
                const bool cv = (unsigned)(x0 - 1 + jj) < HOUT;
                if (!(rowok[i] && cv)) {
                    v[i][jj].x = 0.f; v[i][jj].y = 0.f;
                    v[i][jj].z = 0.f; v[i][jj].w = 0.f;
                }
            }
        }

        // ---- attn runs (contiguous 9 floats each). ----
        const float* a00 = abq + (size_t)t * AHW;
        const float* a01 = a00 + AHW;            // (qy, qx+1) -- used iff hasX
        const float* a10 = a00 + (size_t)HH * AHW;
        const float* a11 = a10 + AHW;
        const bool hasX = (qx < 13);

        const size_t ob = obrow + (size_t)x0 * CC;
        float4 acc;

        // P(0,0)
        acc.x = acc.y = acc.z = acc.w = 0.f;
        fma9<0, 0>(acc, a00 + 4 * 9, v);
        *(float4*)&out[ob] = acc;

        // P(0,1)
        acc.x = acc.y = acc.z = acc.w = 0.f;
        fma9<0, 0>(acc, a00 + 5 * 9, v);
        if (hasX) fma9<0, 2>(acc, a01 + 3 * 9, v);
        *(float4*)&out[ob + CC] = acc;

        // P(1,0)
        acc.x = acc.y = acc.z = acc.w = 0.f;
        fma9<0, 0>(acc, a00 + 7 * 9, v);
        if (hasY) fma9<2, 0>(acc, a10 + 1 * 9, v);
        *(float4*)&out[ob + HOUT * CC] = acc;

        // P(1,1)
        acc.x = acc.y = acc.z = acc.w = 0.f;
        fma9<0, 0>(acc, a00 + 8 * 9, v);
        if (hasX) fma9<0, 2>(acc, a01 + 6 * 9, v);
        if (hasY) fma9<2, 0>(acc, a10 + 2 * 9, v);
        if (hasX && hasY) fma9<2, 2>(acc, a11 + 0 * 9, v);
        *(float4*)&out[ob + (HOUT + 1) * CC] = acc;
    }
}

extern "C" void kernel_launch(void* const* d_in, const int* in_sizes, int n_in,
                              void* d_out, int out_size, void* d_ws, size_t ws_size,
                              hipStream_t stream) {
    const float* vv   = (const float*)d_in[0];
    const float* attn = (const float*)d_in[1];
    float* out        = (float*)d_out;

    const int B = in_sizes[0] / (NPIX * CC);   // elements -> 64
    dim3 grid((unsigned)(B * 28));             // 1792 blocks, 7 quads each
    UnfoldMatmulFold_kernel<<<grid, 192, 0, stream>>>(vv, attn, out);
}